// Round 18
// baseline (116.489 us; speedup 1.0000x reference)
//
#include <hip/hip_runtime.h>

typedef short short8 __attribute__((ext_vector_type(8)));
typedef short short4v __attribute__((ext_vector_type(4)));
typedef float f32x4 __attribute__((ext_vector_type(4)));
typedef float float4v __attribute__((ext_vector_type(4)));
typedef int int4v __attribute__((ext_vector_type(4)));
typedef int int2v __attribute__((ext_vector_type(2)));

__device__ __forceinline__ short f2bf(float f) {
  union { float f; unsigned u; } v; v.f = f;
  unsigned r = v.u + 0x7FFFu + ((v.u >> 16) & 1u);
  return (short)(r >> 16);
}

__device__ __forceinline__ unsigned cvtpk_bf16(float lo, float hi) {
  unsigned r;
  asm("v_cvt_pk_bf16_f32 %0, %1, %2" : "=v"(r) : "v"(lo), "v"(hi));
  return r;  // lo16 = bf16(lo), hi16 = bf16(hi)
}

// async global->LDS, 16B per lane; dest must be linear (wave base + lane*16)
#define GLD16(gp, lp)                                                   \
  __builtin_amdgcn_global_load_lds(                                     \
      (const __attribute__((address_space(1))) void*)(gp),              \
      (__attribute__((address_space(3))) void*)(lp), 16, 0, 0)

// Q scale: softmax uses exp2, so fold log2(e) into the 1/sqrt(64) scale
#define QSCALE 0.18033688011112042f

// ---------------- fused fp32 -> bf16 convert (x | w_qkv | w_proj) ----------------
__global__ __launch_bounds__(256) void cvt_all(
    const float* __restrict__ x, const float* __restrict__ wq, const float* __restrict__ wp,
    short* __restrict__ xb, short* __restrict__ wqb, short* __restrict__ wpb) {
  int i = blockIdx.x * 256 + threadIdx.x;  // in float4 units; total 2097152
  const float* s; short* d; int off;
  if (i < 1048576)      { s = x;  d = xb;  off = i; }
  else if (i < 1835008) { s = wq; d = wqb; off = i - 1048576; }
  else                  { s = wp; d = wpb; off = i - 1835008; }
  float4v v = ((const float4v*)s)[off];
  short4v o;
  o.x = f2bf(v.x); o.y = f2bf(v.y); o.z = f2bf(v.z); o.w = f2bf(v.w);
  ((short4v*)d)[off] = o;
}

// ---------------- qkv GEMM: 256x256 tile, m201-faithful per-phase schedule ----------------
// C[4096,3072] = A[4096,1024] @ Bw[3072,1024]^T + bias -> scatter Q/K/V^T.
// 8 waves (2M x 4N), per-wave 128x64 out (acc[8][4]). BK=64, 16 K-tiles.
// Per-phase discipline (T3+T4+T5, m201/m218b): each of 4 phases per K-tile:
//   stage half-tile p of k+1 -> [mp0: vmcnt(2), barrier, B-frags] ->
//   A-quad ds-reads -> BARRIER -> lgkmcnt(0)+sched_barrier (rule 18) ->
//   setprio(1) 16 MFMA setprio(0) -> BARRIER.
// vmcnt never drains in-loop (2 newest stay in flight); k=15 -> vmcnt(0).
// Overwrite hazard: k's phase-0 stage into buf^1 is after k-1's final
// barrier (all buf^1 reads consumed pre-barrier).
__global__ __launch_bounds__(512, 2) void gemm256(
    const short* __restrict__ A, const short* __restrict__ Bw,
    const float* __restrict__ bias,
    short* __restrict__ qo, short* __restrict__ ko, short* __restrict__ vto) {
  __shared__ char lds[131072];
  const int t = threadIdx.x;
  const int lane = t & 63, wid = t >> 6;
  const int g = lane >> 4, l15 = lane & 15;
  const int wr = wid >> 2, wc = wid & 3;
  const int bid = blockIdx.x;
  // bijective: xcd = bid&7 -> bm = xcd*2 + bit3, bn = bid>>4
  const int bm0 = ((bid & 7) * 2 + ((bid >> 3) & 1)) * 256;
  const int bn0 = (bid >> 4) * 256;

  // staging: linear LDS dest, pre-swizzled source (proven 128B-row swizzle)
  const int srow = t >> 3;
  const int ssub = (t & 7) ^ ((t >> 3) & 7);

  // fragment in-row offsets: (kk*64 + g*16) ^ ((l15&7)<<4), stays in 128B row
  const int swz = (l15 & 7) << 4;
  int inrow[2];
  inrow[0] = (g * 16) ^ swz;
  inrow[1] = (64 + g * 16) ^ swz;
  const int bRow0 = (wc & 1) * 64;  // B rows within its half

  f32x4 acc[8][4] = {};

  // stage half-tile ht (0:Ah0 1:Ah1 2:Bh0 3:Bh1) of K-tile kt into buf b
  auto stageHT = [&](int b, int kt, int ht) {
    const int isB = ht >> 1, hh = ht & 1;
    const short* mat = isB ? Bw : A;
    const int base = isB ? bn0 : bm0;
    const short* src = mat + (size_t)(base + hh * 128 + srow) * 1024 + kt * 64 + ssub * 8;
    char* dst = lds + b * 65536 + isB * 32768 + hh * 16384 + t * 16;
    GLD16(src, dst);                    // rows 0-63 of the half
    GLD16(src + 64 * 1024, dst + 8192); // rows 64-127
  };

  // prologue: K-tile 0's 4 half-tiles (8 loads, FIFO order = ht 0..3)
#pragma unroll
  for (int ht = 0; ht < 4; ++ht) stageHT(0, 0, ht);

  for (int k = 0; k < 16; ++k) {
    const int buf = k & 1;
    const char* Ab = lds + buf * 65536 + wr * 16384;
    const char* Bb = lds + buf * 65536 + 32768 + (wc >> 1) * 16384;
    short8 bB[4][2];
#pragma unroll
    for (int mp = 0; mp < 4; ++mp) {
      // (1) stage half-tile mp of k+1 (2 loads, newest in FIFO)
      if (k + 1 < 16) stageHT(buf ^ 1, k + 1, mp);
      __builtin_amdgcn_sched_barrier(0);
      if (mp == 0) {
        // (2) K-tile k's 8 loads are the oldest; 2 just-issued stay in flight
        if (k + 1 < 16) asm volatile("s_waitcnt vmcnt(2)" ::: "memory");
        else            asm volatile("s_waitcnt vmcnt(0)" ::: "memory");
        __builtin_amdgcn_s_barrier();   // all waves: tile k staged
        __builtin_amdgcn_sched_barrier(0);
#pragma unroll
        for (int n = 0; n < 4; ++n)
#pragma unroll
          for (int kk = 0; kk < 2; ++kk)
            bB[n][kk] = *(const short8*)(Bb + (bRow0 + n * 16 + l15) * 128 + inrow[kk]);
      }
      // (3) issue this quadrant's A-frag reads (latency spans the barrier)
      short8 aA[2][2];
#pragma unroll
      for (int mm = 0; mm < 2; ++mm)
#pragma unroll
        for (int kk = 0; kk < 2; ++kk)
          aA[mm][kk] = *(const short8*)(Ab + ((mp * 2 + mm) * 16 + l15) * 128 + inrow[kk]);
      // (4) phase-sync: all waves enter MFMA together (role-split per phase)
      __builtin_amdgcn_s_barrier();
      asm volatile("s_waitcnt lgkmcnt(0)" ::: "memory");
      __builtin_amdgcn_sched_barrier(0);  // rule 18: fence MFMA after lgkmcnt
      __builtin_amdgcn_s_setprio(1);
#pragma unroll
      for (int mm = 0; mm < 2; ++mm)
#pragma unroll
        for (int n = 0; n < 4; ++n)
#pragma unroll
          for (int kk = 0; kk < 2; ++kk)
            acc[mp * 2 + mm][n] = __builtin_amdgcn_mfma_f32_16x16x32_bf16(
                aA[mm][kk], bB[n][kk], acc[mp * 2 + mm][n], 0, 0, 0);
      __builtin_amdgcn_s_setprio(0);
      __builtin_amdgcn_sched_barrier(0);
      __builtin_amdgcn_s_barrier();       // end-of-phase
      __builtin_amdgcn_sched_barrier(0);
    }
  }

  // epilogue: scatter Q (scaled), K, V^T(bit-permuted) — which is block-uniform
  const int which = bn0 >> 10;
  if (which == 2) {
#pragma unroll
    for (int m = 0; m < 8; ++m) {
#pragma unroll
      for (int n = 0; n < 4; ++n) {
        int gcol = bn0 + wc * 64 + n * 16 + l15;
        int w1 = gcol & 1023;
        int h = w1 >> 6, dd = w1 & 63;
        float bv = bias[gcol];
        int grow0 = bm0 + wr * 128 + m * 16 + g * 4;
        int b_ = grow0 >> 11, n0 = grow0 & 2047;
        int bh = b_ * 16 + h;
        int nl = n0 & 63;
        // kv bit-perm [b5][b3][b2][b4][b1][b0]; n0 4-aligned -> np too
        int np = (n0 & ~63) | (nl & 32) | ((nl & 12) << 1) | ((nl & 16) >> 2);
        int2v pk;
        pk.x = (int)cvtpk_bf16(acc[m][n][0] + bv, acc[m][n][1] + bv);
        pk.y = (int)cvtpk_bf16(acc[m][n][2] + bv, acc[m][n][3] + bv);
        *(int2v*)(vto + ((size_t)bh * 64 + dd) * 2048 + np) = pk;
      }
    }
  } else {
    short* dst = (which == 0) ? qo : ko;
    const float sc = (which == 0) ? QSCALE : 1.0f;
#pragma unroll
    for (int m = 0; m < 8; ++m) {
#pragma unroll
      for (int n = 0; n < 4; ++n) {
        int gcol = bn0 + wc * 64 + n * 16 + l15;
        int w1 = gcol & 1023;
        int h = w1 >> 6, dd = w1 & 63;
        float bv = bias[gcol];
#pragma unroll
        for (int r = 0; r < 4; ++r) {
          int grow = bm0 + wr * 128 + m * 16 + g * 4 + r;
          int b_ = grow >> 11, n2 = grow & 2047;
          int bh = b_ * 16 + h;
          dst[((size_t)bh * 2048 + n2) * 64 + dd] = f2bf((acc[m][n][r] + bv) * sc);
        }
      }
    }
  }
}

// ---------------- proj GEMM (R14-proven): BK=32, 3 slots, depth-3 vmcnt ----------------
__global__ __launch_bounds__(256, 3) void gemm_proj(
    const short* __restrict__ A, const short* __restrict__ Bw,
    const float* __restrict__ bias, float* __restrict__ outf) {
  __shared__ short As[3][128 * 32];
  __shared__ short Bs[3][128 * 32];
  const int t = threadIdx.x;
  const int lane = t & 63, wid = t >> 6;
  const int g = lane >> 4, l15 = lane & 15;
  const int wr = (wid >> 1) * 64, wc = (wid & 1) * 64;
  const int bid = blockIdx.x;
  const int bm0 = ((bid & 7) * 4 + ((bid >> 3) & 3)) * 128;
  const int bn0 = (bid >> 5) * 128;

  const int sr = t >> 2;
  const int csrc = (t & 3) ^ ((t >> 3) & 3);

  const int gx = (g ^ ((l15 >> 1) & 3)) << 4;
  int aoff[4], boff[4];
#pragma unroll
  for (int f = 0; f < 4; ++f) {
    aoff[f] = (wr + f * 16 + l15) * 64 + gx;
    boff[f] = (wc + f * 16 + l15) * 64 + gx;
  }

  f32x4 acc[4][4] = {};

  auto stage = [&](int offB, int k0) {
#pragma unroll
    for (int i = 0; i < 2; ++i) {
      int row = i * 64 + sr;
      char* ldsA = (char*)&As[0][0] + offB + (i * 256 + (t & ~63)) * 16;
      char* ldsB = (char*)&Bs[0][0] + offB + (i * 256 + (t & ~63)) * 16;
      GLD16(A + (size_t)(bm0 + row) * 1024 + k0 + csrc * 8, ldsA);
      GLD16(Bw + (size_t)(bn0 + row) * 1024 + k0 + csrc * 8, ldsB);
    }
  };

  stage(0, 0);
  stage(8192, 32);
  stage(16384, 64);
  int off = 0;

  for (int it = 0; it < 32; ++it) {
    if (it < 30)       asm volatile("s_waitcnt vmcnt(8)" ::: "memory");
    else if (it == 30) asm volatile("s_waitcnt vmcnt(4)" ::: "memory");
    else               asm volatile("s_waitcnt vmcnt(0)" ::: "memory");
    __builtin_amdgcn_s_barrier();
    __builtin_amdgcn_sched_barrier(0);
    const char* AsB = (const char*)&As[0][0] + off;
    const char* BsB = (const char*)&Bs[0][0] + off;
    short8 a[4], b[4];
#pragma unroll
    for (int mi = 0; mi < 4; ++mi) a[mi] = *(const short8*)(AsB + aoff[mi]);
#pragma unroll
    for (int ni = 0; ni < 4; ++ni) b[ni] = *(const short8*)(BsB + boff[ni]);
#pragma unroll
    for (int mi = 0; mi < 4; ++mi)
#pragma unroll
      for (int ni = 0; ni < 4; ++ni)
        acc[mi][ni] = __builtin_amdgcn_mfma_f32_16x16x32_bf16(a[mi], b[ni], acc[mi][ni], 0, 0, 0);
    __builtin_amdgcn_sched_barrier(0);
    __builtin_amdgcn_s_barrier();
    __builtin_amdgcn_sched_barrier(0);
    if (it + 3 < 32) stage(off, (it + 3) * 32);
    off = (off == 16384) ? 0 : off + 8192;
  }

#pragma unroll
  for (int mi = 0; mi < 4; ++mi) {
#pragma unroll
    for (int ni = 0; ni < 4; ++ni) {
      int gcol = bn0 + wc + ni * 16 + l15;
      float bv = bias[gcol];
#pragma unroll
      for (int r = 0; r < 4; ++r) {
        int grow = bm0 + wr + mi * 16 + g * 4 + r;
        outf[(size_t)grow * 1024 + gcol] = acc[mi][ni][r] + bv;
      }
    }
  }
}

// ---------------- flash attention (R10-proven, 58.7us — attn floor) ----------------
__global__ __launch_bounds__(256, 2) void attn_fused(
    const short* __restrict__ Qg, const short* __restrict__ Kg,
    const short* __restrict__ Vtg, short* __restrict__ AO) {
  __shared__ short Ks[4][64 * 64];  // slot = buf*2 + sub, 8KB each
  __shared__ short Vs[4][64 * 64];
  const int bid = blockIdx.x;
  const int bh = bid & 31, qt = bid >> 5;
  const int t = threadIdx.x, wid = t >> 6, lane = t & 63;
  const int g = lane >> 4, l15 = lane & 15;
  const int q0w = qt * 128 + wid * 32;
  const short* qb = Qg + ((size_t)bh * 2048 + q0w) * 64;
  const short* kb = Kg + (size_t)bh * 2048 * 64;
  const short* vb = Vtg + (size_t)bh * 64 * 2048;

  const int srow = t >> 3;
  const int ssub = (t & 7) ^ (srow & 7);
  const short* ksrc0 = kb + srow * 64 + ssub * 8;
  const short* vsrc0 = vb + (size_t)srow * 2048 + ssub * 8;

  const int swz = (l15 & 7) << 4;
  int foff[2][4];
#pragma unroll
  for (int kk = 0; kk < 2; ++kk)
#pragma unroll
    for (int f = 0; f < 4; ++f)
      foff[kk][f] = ((f * 16 + l15) * 128 + kk * 64 + g * 16) ^ swz;

  short8 bq[2][2];
#pragma unroll
  for (int qf = 0; qf < 2; ++qf)
#pragma unroll
    for (int kk = 0; kk < 2; ++kk)
      bq[qf][kk] = *(const short8*)(qb + (qf * 16 + l15) * 64 + kk * 32 + g * 8);

  auto stageP = [&](int buf, int p) {
    const int n0 = p * 128;
#pragma unroll
    for (int sub = 0; sub < 2; ++sub) {
      const int nn = n0 + sub * 64;
      char* ldsK = (char*)&Ks[buf * 2 + sub][0] + wid * 1024;
      char* ldsV = (char*)&Vs[buf * 2 + sub][0] + wid * 1024;
#pragma unroll
      for (int i = 0; i < 2; ++i) {
        GLD16(ksrc0 + (size_t)(nn + i * 32) * 64, ldsK + i * 4096);
        GLD16(vsrc0 + (size_t)i * 32 * 2048 + nn, ldsV + i * 4096);
      }
    }
  };

  stageP(0, 0);
  stageP(1, 1);

  f32x4 acc[2][4] = {};
  float mrun[2] = {-3.0e38f, -3.0e38f}, lrun[2] = {0.f, 0.f};

  for (int p = 0; p < 16; ++p) {
    if (p == 15) asm volatile("s_waitcnt vmcnt(0)" ::: "memory");
    else         asm volatile("s_waitcnt vmcnt(8)" ::: "memory");
    __builtin_amdgcn_s_barrier();
    __builtin_amdgcn_sched_barrier(0);
    const int buf = p & 1;

#pragma unroll
    for (int sub = 0; sub < 2; ++sub) {
      const char* KsB = (const char*)&Ks[buf * 2 + sub][0];
      const char* VsB = (const char*)&Vs[buf * 2 + sub][0];

      f32x4 s[2][4] = {};
#pragma unroll
      for (int kk = 0; kk < 2; ++kk) {
        short8 ak[4];
#pragma unroll
        for (int kf = 0; kf < 4; ++kf) ak[kf] = *(const short8*)(KsB + foff[kk][kf]);
#pragma unroll
        for (int kf = 0; kf < 4; ++kf)
#pragma unroll
          for (int qf = 0; qf < 2; ++qf)
            s[qf][kf] = __builtin_amdgcn_mfma_f32_16x16x32_bf16(ak[kf], bq[qf][kk], s[qf][kf], 0, 0, 0);
      }

      float pm[2];
#pragma unroll
      for (int qf = 0; qf < 2; ++qf) {
        float m0 = fmaxf(s[qf][0][0], s[qf][0][1]);
        m0 = fmaxf(fmaxf(m0, s[qf][0][2]), s[qf][0][3]);
#pragma unroll
        for (int kf = 1; kf < 4; ++kf) {
          m0 = fmaxf(fmaxf(m0, s[qf][kf][0]), s[qf][kf][1]);
          m0 = fmaxf(fmaxf(m0, s[qf][kf][2]), s[qf][kf][3]);
        }
        float x = fmaxf(m0, __shfl_xor(m0, 16));
        pm[qf] = fmaxf(x, __shfl_xor(x, 32));
      }

      if (!__all((pm[0] - mrun[0] <= 8.f) && (pm[1] - mrun[1] <= 8.f))) {
#pragma unroll
        for (int qf = 0; qf < 2; ++qf) {
          float mn = fmaxf(mrun[qf], pm[qf]);
          float alpha = __builtin_amdgcn_exp2f(mrun[qf] - mn);
          mrun[qf] = mn;
          lrun[qf] *= alpha;
#pragma unroll
          for (int df = 0; df < 4; ++df)
#pragma unroll
            for (int r = 0; r < 4; ++r) acc[qf][df][r] *= alpha;
        }
      }

      unsigned wpk[2][4][2];
#pragma unroll
      for (int qf = 0; qf < 2; ++qf) {
        float rs = 0.f;
        float pp[4][4];
#pragma unroll
        for (int kf = 0; kf < 4; ++kf)
#pragma unroll
          for (int r = 0; r < 4; ++r) {
            pp[kf][r] = __builtin_amdgcn_exp2f(s[qf][kf][r] - mrun[qf]);
            rs += pp[kf][r];
          }
        rs += __shfl_xor(rs, 16);
        rs += __shfl_xor(rs, 32);
        lrun[qf] += rs;
#pragma unroll
        for (int kf = 0; kf < 4; ++kf)
#pragma unroll
          for (int h = 0; h < 2; ++h)
            wpk[qf][kf][h] = cvtpk_bf16(pp[kf][2 * h], pp[kf][2 * h + 1]);
      }

#pragma unroll
      for (int kk = 0; kk < 2; ++kk) {
        short8 av[4];
#pragma unroll
        for (int df = 0; df < 4; ++df) av[df] = *(const short8*)(VsB + foff[kk][df]);
#pragma unroll
        for (int qf = 0; qf < 2; ++qf) {
          union { int4v i; short8 s; } pv;
          pv.i[0] = (int)wpk[qf][2 * kk][0];
          pv.i[1] = (int)wpk[qf][2 * kk][1];
          pv.i[2] = (int)wpk[qf][2 * kk + 1][0];
          pv.i[3] = (int)wpk[qf][2 * kk + 1][1];
#pragma unroll
          for (int df = 0; df < 4; ++df)
            acc[qf][df] = __builtin_amdgcn_mfma_f32_16x16x32_bf16(av[df], pv.s, acc[qf][df], 0, 0, 0);
        }
      }
    }

    __builtin_amdgcn_sched_barrier(0);
    __builtin_amdgcn_s_barrier();
    __builtin_amdgcn_sched_barrier(0);
    if (p + 2 < 16) stageP(buf, p + 2);
  }

  const int b_ = bh >> 4, h = bh & 15;
#pragma unroll
  for (int qf = 0; qf < 2; ++qf) {
    const float inv = 1.0f / lrun[qf];
    short* outp = AO + ((size_t)b_ * 2048 + q0w + qf * 16 + l15) * 1024 + h * 64 + g * 4;
#pragma unroll
    for (int df = 0; df < 4; ++df) {
      short4v o;
#pragma unroll
      for (int r = 0; r < 4; ++r) o[r] = f2bf(acc[qf][df][r] * inv);
      *(short4v*)(outp + df * 16) = o;
    }
  }
}

// ---------------- launch ----------------
extern "C" void kernel_launch(void* const* d_in, const int* in_sizes, int n_in,
                              void* d_out, int out_size, void* d_ws, size_t ws_size,
                              hipStream_t stream) {
  const float* x = (const float*)d_in[0];
  const float* w_qkv = (const float*)d_in[1];
  const float* b_qkv = (const float*)d_in[2];
  const float* w_proj = (const float*)d_in[3];
  const float* b_proj = (const float*)d_in[4];
  float* out = (float*)d_out;
  char* ws = (char*)d_ws;

  short* xb    = (short*)(ws + (size_t)0);
  short* wqkvb = (short*)(ws + ((size_t)8 << 20));
  short* wprojb= (short*)(ws + ((size_t)14 << 20));
  short* qb    = (short*)(ws + ((size_t)16 << 20));
  short* kb    = (short*)(ws + ((size_t)24 << 20));
  short* vtb   = (short*)(ws + ((size_t)32 << 20));
  short* aob   = (short*)(ws + ((size_t)40 << 20));

  cvt_all<<<8192, 256, 0, stream>>>(x, w_qkv, w_proj, xb, wqkvb, wprojb);
  gemm256<<<192, 512, 0, stream>>>(xb, wqkvb, b_qkv, qb, kb, vtb);
  attn_fused<<<512, 256, 0, stream>>>(qb, kb, vtb, aob);
  gemm_proj<<<256, 256, 0, stream>>>(aob, wprojb, b_proj, out);
}

// Round 20
// 115.143 us; speedup vs baseline: 1.0117x; 1.0117x over previous
//
#include <hip/hip_runtime.h>

typedef short short8 __attribute__((ext_vector_type(8)));
typedef short short4v __attribute__((ext_vector_type(4)));
typedef float f32x4 __attribute__((ext_vector_type(4)));
typedef float float4v __attribute__((ext_vector_type(4)));
typedef int int4v __attribute__((ext_vector_type(4)));
typedef int int2v __attribute__((ext_vector_type(2)));

__device__ __forceinline__ short f2bf(float f) {
  union { float f; unsigned u; } v; v.f = f;
  unsigned r = v.u + 0x7FFFu + ((v.u >> 16) & 1u);
  return (short)(r >> 16);
}

__device__ __forceinline__ unsigned cvtpk_bf16(float lo, float hi) {
  unsigned r;
  asm("v_cvt_pk_bf16_f32 %0, %1, %2" : "=v"(r) : "v"(lo), "v"(hi));
  return r;  // lo16 = bf16(lo), hi16 = bf16(hi)
}

// async global->LDS, 16B per lane; dest must be linear (wave base + lane*16)
#define GLD16(gp, lp)                                                   \
  __builtin_amdgcn_global_load_lds(                                     \
      (const __attribute__((address_space(1))) void*)(gp),              \
      (__attribute__((address_space(3))) void*)(lp), 16, 0, 0)

// Q scale: softmax uses exp2, so fold log2(e) into the 1/sqrt(64) scale
#define QSCALE 0.18033688011112042f

// ---------------- fused fp32 -> bf16 convert (x | w_qkv | w_proj) ----------------
__global__ __launch_bounds__(256) void cvt_all(
    const float* __restrict__ x, const float* __restrict__ wq, const float* __restrict__ wp,
    short* __restrict__ xb, short* __restrict__ wqb, short* __restrict__ wpb) {
  int i = blockIdx.x * 256 + threadIdx.x;  // in float4 units; total 2097152
  const float* s; short* d; int off;
  if (i < 1048576)      { s = x;  d = xb;  off = i; }
  else if (i < 1835008) { s = wq; d = wqb; off = i - 1048576; }
  else                  { s = wp; d = wpb; off = i - 1835008; }
  float4v v = ((const float4v*)s)[off];
  short4v o;
  o.x = f2bf(v.x); o.y = f2bf(v.y); o.z = f2bf(v.z); o.w = f2bf(v.w);
  ((short4v*)d)[off] = o;
}

// ---------------- qkv GEMM: 256x256 tile, 4-phase/K-tile counted-vmcnt (R17) ----------------
__global__ __launch_bounds__(512, 2) void gemm256(
    const short* __restrict__ A, const short* __restrict__ Bw,
    const float* __restrict__ bias,
    short* __restrict__ qo, short* __restrict__ ko, short* __restrict__ vto) {
  __shared__ char lds[131072];
  const int t = threadIdx.x;
  const int lane = t & 63, wid = t >> 6;
  const int g = lane >> 4, l15 = lane & 15;
  const int wr = wid >> 2, wc = wid & 3;
  const int bid = blockIdx.x;
  // bijective: xcd = bid&7 -> bm = xcd*2 + bit3, bn = bid>>4
  const int bm0 = ((bid & 7) * 2 + ((bid >> 3) & 1)) * 256;
  const int bn0 = (bid >> 4) * 256;

  const int srow = t >> 3;
  const int ssub = (t & 7) ^ ((t >> 3) & 7);

  const int swz = (l15 & 7) << 4;
  int inrow[2];
  inrow[0] = (g * 16) ^ swz;
  inrow[1] = (64 + g * 16) ^ swz;
  const int bRow0 = (wc & 1) * 64;

  f32x4 acc[8][4] = {};

  auto stageHT = [&](int b, int kt, int ht) {
    const int isB = ht >> 1, hh = ht & 1;
    const short* mat = isB ? Bw : A;
    const int base = isB ? bn0 : bm0;
    const short* src = mat + (size_t)(base + hh * 128 + srow) * 1024 + kt * 64 + ssub * 8;
    char* dst = lds + b * 65536 + isB * 32768 + hh * 16384 + t * 16;
    GLD16(src, dst);
    GLD16(src + 64 * 1024, dst + 8192);
  };

#pragma unroll
  for (int ht = 0; ht < 4; ++ht) stageHT(0, 0, ht);

  for (int k = 0; k < 16; ++k) {
    const int buf = k & 1;
    const char* Ab = lds + buf * 65536 + wr * 16384;
    const char* Bb = lds + buf * 65536 + 32768 + (wc >> 1) * 16384;
    short8 bB[4][2];
#pragma unroll
    for (int mp = 0; mp < 4; ++mp) {
      if (k + 1 < 16) stageHT(buf ^ 1, k + 1, mp);
      __builtin_amdgcn_sched_barrier(0);
      if (mp == 0) {
        if (k + 1 < 16) asm volatile("s_waitcnt vmcnt(2)" ::: "memory");
        else            asm volatile("s_waitcnt vmcnt(0)" ::: "memory");
        __builtin_amdgcn_s_barrier();
        __builtin_amdgcn_sched_barrier(0);
#pragma unroll
        for (int n = 0; n < 4; ++n)
#pragma unroll
          for (int kk = 0; kk < 2; ++kk)
            bB[n][kk] = *(const short8*)(Bb + (bRow0 + n * 16 + l15) * 128 + inrow[kk]);
      }
      short8 aA[2][2];
#pragma unroll
      for (int mm = 0; mm < 2; ++mm)
#pragma unroll
        for (int kk = 0; kk < 2; ++kk)
          aA[mm][kk] = *(const short8*)(Ab + ((mp * 2 + mm) * 16 + l15) * 128 + inrow[kk]);
      __builtin_amdgcn_s_setprio(1);
#pragma unroll
      for (int mm = 0; mm < 2; ++mm)
#pragma unroll
        for (int n = 0; n < 4; ++n)
#pragma unroll
          for (int kk = 0; kk < 2; ++kk)
            acc[mp * 2 + mm][n] = __builtin_amdgcn_mfma_f32_16x16x32_bf16(
                aA[mm][kk], bB[n][kk], acc[mp * 2 + mm][n], 0, 0, 0);
      __builtin_amdgcn_s_setprio(0);
      if (mp == 3) {
        __builtin_amdgcn_sched_barrier(0);
        __builtin_amdgcn_s_barrier();
        __builtin_amdgcn_sched_barrier(0);
      }
    }
  }

  const int which = bn0 >> 10;
  if (which == 2) {
#pragma unroll
    for (int m = 0; m < 8; ++m) {
#pragma unroll
      for (int n = 0; n < 4; ++n) {
        int gcol = bn0 + wc * 64 + n * 16 + l15;
        int w1 = gcol & 1023;
        int h = w1 >> 6, dd = w1 & 63;
        float bv = bias[gcol];
        int grow0 = bm0 + wr * 128 + m * 16 + g * 4;
        int b_ = grow0 >> 11, n0 = grow0 & 2047;
        int bh = b_ * 16 + h;
        int nl = n0 & 63;
        int np = (n0 & ~63) | (nl & 32) | ((nl & 12) << 1) | ((nl & 16) >> 2);
        int2v pk;
        pk.x = (int)cvtpk_bf16(acc[m][n][0] + bv, acc[m][n][1] + bv);
        pk.y = (int)cvtpk_bf16(acc[m][n][2] + bv, acc[m][n][3] + bv);
        *(int2v*)(vto + ((size_t)bh * 64 + dd) * 2048 + np) = pk;
      }
    }
  } else {
    short* dst = (which == 0) ? qo : ko;
    const float sc = (which == 0) ? QSCALE : 1.0f;
#pragma unroll
    for (int m = 0; m < 8; ++m) {
#pragma unroll
      for (int n = 0; n < 4; ++n) {
        int gcol = bn0 + wc * 64 + n * 16 + l15;
        int w1 = gcol & 1023;
        int h = w1 >> 6, dd = w1 & 63;
        float bv = bias[gcol];
#pragma unroll
        for (int r = 0; r < 4; ++r) {
          int grow = bm0 + wr * 128 + m * 16 + g * 4 + r;
          int b_ = grow >> 11, n2 = grow & 2047;
          int bh = b_ * 16 + h;
          dst[((size_t)bh * 2048 + n2) * 64 + dd] = f2bf((acc[m][n][r] + bv) * sc);
        }
      }
    }
  }
}

// ---------------- proj GEMM (R14-proven): BK=32, 3 slots, depth-3 vmcnt ----------------
__global__ __launch_bounds__(256, 3) void gemm_proj(
    const short* __restrict__ A, const short* __restrict__ Bw,
    const float* __restrict__ bias, float* __restrict__ outf) {
  __shared__ short As[3][128 * 32];
  __shared__ short Bs[3][128 * 32];
  const int t = threadIdx.x;
  const int lane = t & 63, wid = t >> 6;
  const int g = lane >> 4, l15 = lane & 15;
  const int wr = (wid >> 1) * 64, wc = (wid & 1) * 64;
  const int bid = blockIdx.x;
  const int bm0 = ((bid & 7) * 4 + ((bid >> 3) & 3)) * 128;
  const int bn0 = (bid >> 5) * 128;

  const int sr = t >> 2;
  const int csrc = (t & 3) ^ ((t >> 3) & 3);

  const int gx = (g ^ ((l15 >> 1) & 3)) << 4;
  int aoff[4], boff[4];
#pragma unroll
  for (int f = 0; f < 4; ++f) {
    aoff[f] = (wr + f * 16 + l15) * 64 + gx;
    boff[f] = (wc + f * 16 + l15) * 64 + gx;
  }

  f32x4 acc[4][4] = {};

  auto stage = [&](int offB, int k0) {
#pragma unroll
    for (int i = 0; i < 2; ++i) {
      int row = i * 64 + sr;
      char* ldsA = (char*)&As[0][0] + offB + (i * 256 + (t & ~63)) * 16;
      char* ldsB = (char*)&Bs[0][0] + offB + (i * 256 + (t & ~63)) * 16;
      GLD16(A + (size_t)(bm0 + row) * 1024 + k0 + csrc * 8, ldsA);
      GLD16(Bw + (size_t)(bn0 + row) * 1024 + k0 + csrc * 8, ldsB);
    }
  };

  stage(0, 0);
  stage(8192, 32);
  stage(16384, 64);
  int off = 0;

  for (int it = 0; it < 32; ++it) {
    if (it < 30)       asm volatile("s_waitcnt vmcnt(8)" ::: "memory");
    else if (it == 30) asm volatile("s_waitcnt vmcnt(4)" ::: "memory");
    else               asm volatile("s_waitcnt vmcnt(0)" ::: "memory");
    __builtin_amdgcn_s_barrier();
    __builtin_amdgcn_sched_barrier(0);
    const char* AsB = (const char*)&As[0][0] + off;
    const char* BsB = (const char*)&Bs[0][0] + off;
    short8 a[4], b[4];
#pragma unroll
    for (int mi = 0; mi < 4; ++mi) a[mi] = *(const short8*)(AsB + aoff[mi]);
#pragma unroll
    for (int ni = 0; ni < 4; ++ni) b[ni] = *(const short8*)(BsB + boff[ni]);
#pragma unroll
    for (int mi = 0; mi < 4; ++mi)
#pragma unroll
      for (int ni = 0; ni < 4; ++ni)
        acc[mi][ni] = __builtin_amdgcn_mfma_f32_16x16x32_bf16(a[mi], b[ni], acc[mi][ni], 0, 0, 0);
    __builtin_amdgcn_sched_barrier(0);
    __builtin_amdgcn_s_barrier();
    __builtin_amdgcn_sched_barrier(0);
    if (it + 3 < 32) stage(off, (it + 3) * 32);
    off = (off == 16384) ? 0 : off + 8192;
  }

#pragma unroll
  for (int mi = 0; mi < 4; ++mi) {
#pragma unroll
    for (int ni = 0; ni < 4; ++ni) {
      int gcol = bn0 + wc + ni * 16 + l15;
      float bv = bias[gcol];
#pragma unroll
      for (int r = 0; r < 4; ++r) {
        int grow = bm0 + wr + mi * 16 + g * 4 + r;
        outf[(size_t)grow * 1024 + gcol] = acc[mi][ni][r] + bv;
      }
    }
  }
}

// ---------------- flash attention (R10-proven, 58.7us, defer-max) ----------------
// R19's fixed-base softmax (no max subtraction) FAILED precision (absmax
// 0.0376 vs 0.0057 threshold) — mechanism not identified, reverted.
__global__ __launch_bounds__(256, 2) void attn_fused(
    const short* __restrict__ Qg, const short* __restrict__ Kg,
    const short* __restrict__ Vtg, short* __restrict__ AO) {
  __shared__ short Ks[4][64 * 64];  // slot = buf*2 + sub, 8KB each
  __shared__ short Vs[4][64 * 64];
  const int bid = blockIdx.x;
  const int bh = bid & 31, qt = bid >> 5;
  const int t = threadIdx.x, wid = t >> 6, lane = t & 63;
  const int g = lane >> 4, l15 = lane & 15;
  const int q0w = qt * 128 + wid * 32;
  const short* qb = Qg + ((size_t)bh * 2048 + q0w) * 64;
  const short* kb = Kg + (size_t)bh * 2048 * 64;
  const short* vb = Vtg + (size_t)bh * 64 * 2048;

  const int srow = t >> 3;
  const int ssub = (t & 7) ^ (srow & 7);
  const short* ksrc0 = kb + srow * 64 + ssub * 8;
  const short* vsrc0 = vb + (size_t)srow * 2048 + ssub * 8;

  const int swz = (l15 & 7) << 4;
  int foff[2][4];
#pragma unroll
  for (int kk = 0; kk < 2; ++kk)
#pragma unroll
    for (int f = 0; f < 4; ++f)
      foff[kk][f] = ((f * 16 + l15) * 128 + kk * 64 + g * 16) ^ swz;

  short8 bq[2][2];
#pragma unroll
  for (int qf = 0; qf < 2; ++qf)
#pragma unroll
    for (int kk = 0; kk < 2; ++kk)
      bq[qf][kk] = *(const short8*)(qb + (qf * 16 + l15) * 64 + kk * 32 + g * 8);

  auto stageP = [&](int buf, int p) {
    const int n0 = p * 128;
#pragma unroll
    for (int sub = 0; sub < 2; ++sub) {
      const int nn = n0 + sub * 64;
      char* ldsK = (char*)&Ks[buf * 2 + sub][0] + wid * 1024;
      char* ldsV = (char*)&Vs[buf * 2 + sub][0] + wid * 1024;
#pragma unroll
      for (int i = 0; i < 2; ++i) {
        GLD16(ksrc0 + (size_t)(nn + i * 32) * 64, ldsK + i * 4096);
        GLD16(vsrc0 + (size_t)i * 32 * 2048 + nn, ldsV + i * 4096);
      }
    }
  };

  stageP(0, 0);
  stageP(1, 1);

  f32x4 acc[2][4] = {};
  float mrun[2] = {-3.0e38f, -3.0e38f}, lrun[2] = {0.f, 0.f};

  for (int p = 0; p < 16; ++p) {
    if (p == 15) asm volatile("s_waitcnt vmcnt(0)" ::: "memory");
    else         asm volatile("s_waitcnt vmcnt(8)" ::: "memory");
    __builtin_amdgcn_s_barrier();
    __builtin_amdgcn_sched_barrier(0);
    const int buf = p & 1;

#pragma unroll
    for (int sub = 0; sub < 2; ++sub) {
      const char* KsB = (const char*)&Ks[buf * 2 + sub][0];
      const char* VsB = (const char*)&Vs[buf * 2 + sub][0];

      f32x4 s[2][4] = {};
#pragma unroll
      for (int kk = 0; kk < 2; ++kk) {
        short8 ak[4];
#pragma unroll
        for (int kf = 0; kf < 4; ++kf) ak[kf] = *(const short8*)(KsB + foff[kk][kf]);
#pragma unroll
        for (int kf = 0; kf < 4; ++kf)
#pragma unroll
          for (int qf = 0; qf < 2; ++qf)
            s[qf][kf] = __builtin_amdgcn_mfma_f32_16x16x32_bf16(ak[kf], bq[qf][kk], s[qf][kf], 0, 0, 0);
      }

      float pm[2];
#pragma unroll
      for (int qf = 0; qf < 2; ++qf) {
        float m0 = fmaxf(s[qf][0][0], s[qf][0][1]);
        m0 = fmaxf(fmaxf(m0, s[qf][0][2]), s[qf][0][3]);
#pragma unroll
        for (int kf = 1; kf < 4; ++kf) {
          m0 = fmaxf(fmaxf(m0, s[qf][kf][0]), s[qf][kf][1]);
          m0 = fmaxf(fmaxf(m0, s[qf][kf][2]), s[qf][kf][3]);
        }
        float x = fmaxf(m0, __shfl_xor(m0, 16));
        pm[qf] = fmaxf(x, __shfl_xor(x, 32));
      }

      if (!__all((pm[0] - mrun[0] <= 8.f) && (pm[1] - mrun[1] <= 8.f))) {
#pragma unroll
        for (int qf = 0; qf < 2; ++qf) {
          float mn = fmaxf(mrun[qf], pm[qf]);
          float alpha = __builtin_amdgcn_exp2f(mrun[qf] - mn);
          mrun[qf] = mn;
          lrun[qf] *= alpha;
#pragma unroll
          for (int df = 0; df < 4; ++df)
#pragma unroll
            for (int r = 0; r < 4; ++r) acc[qf][df][r] *= alpha;
        }
      }

      unsigned wpk[2][4][2];
#pragma unroll
      for (int qf = 0; qf < 2; ++qf) {
        float rs = 0.f;
        float pp[4][4];
#pragma unroll
        for (int kf = 0; kf < 4; ++kf)
#pragma unroll
          for (int r = 0; r < 4; ++r) {
            pp[kf][r] = __builtin_amdgcn_exp2f(s[qf][kf][r] - mrun[qf]);
            rs += pp[kf][r];
          }
        rs += __shfl_xor(rs, 16);
        rs += __shfl_xor(rs, 32);
        lrun[qf] += rs;
#pragma unroll
        for (int kf = 0; kf < 4; ++kf)
#pragma unroll
          for (int h = 0; h < 2; ++h)
            wpk[qf][kf][h] = cvtpk_bf16(pp[kf][2 * h], pp[kf][2 * h + 1]);
      }

#pragma unroll
      for (int kk = 0; kk < 2; ++kk) {
        short8 av[4];
#pragma unroll
        for (int df = 0; df < 4; ++df) av[df] = *(const short8*)(VsB + foff[kk][df]);
#pragma unroll
        for (int qf = 0; qf < 2; ++qf) {
          union { int4v i; short8 s; } pv;
          pv.i[0] = (int)wpk[qf][2 * kk][0];
          pv.i[1] = (int)wpk[qf][2 * kk][1];
          pv.i[2] = (int)wpk[qf][2 * kk + 1][0];
          pv.i[3] = (int)wpk[qf][2 * kk + 1][1];
#pragma unroll
          for (int df = 0; df < 4; ++df)
            acc[qf][df] = __builtin_amdgcn_mfma_f32_16x16x32_bf16(av[df], pv.s, acc[qf][df], 0, 0, 0);
        }
      }
    }

    __builtin_amdgcn_sched_barrier(0);
    __builtin_amdgcn_s_barrier();
    __builtin_amdgcn_sched_barrier(0);
    if (p + 2 < 16) stageP(buf, p + 2);
  }

  const int b_ = bh >> 4, h = bh & 15;
#pragma unroll
  for (int qf = 0; qf < 2; ++qf) {
    const float inv = 1.0f / lrun[qf];
    short* outp = AO + ((size_t)b_ * 2048 + q0w + qf * 16 + l15) * 1024 + h * 64 + g * 4;
#pragma unroll
    for (int df = 0; df < 4; ++df) {
      short4v o;
#pragma unroll
      for (int r = 0; r < 4; ++r) o[r] = f2bf(acc[qf][df][r] * inv);
      *(short4v*)(outp + df * 16) = o;
    }
  }
}

// ---------------- launch ----------------
extern "C" void kernel_launch(void* const* d_in, const int* in_sizes, int n_in,
                              void* d_out, int out_size, void* d_ws, size_t ws_size,
                              hipStream_t stream) {
  const float* x = (const float*)d_in[0];
  const float* w_qkv = (const float*)d_in[1];
  const float* b_qkv = (const float*)d_in[2];
  const float* w_proj = (const float*)d_in[3];
  const float* b_proj = (const float*)d_in[4];
  float* out = (float*)d_out;
  char* ws = (char*)d_ws;

  short* xb    = (short*)(ws + (size_t)0);
  short* wqkvb = (short*)(ws + ((size_t)8 << 20));
  short* wprojb= (short*)(ws + ((size_t)14 << 20));
  short* qb    = (short*)(ws + ((size_t)16 << 20));
  short* kb    = (short*)(ws + ((size_t)24 << 20));
  short* vtb   = (short*)(ws + ((size_t)32 << 20));
  short* aob   = (short*)(ws + ((size_t)40 << 20));

  cvt_all<<<8192, 256, 0, stream>>>(x, w_qkv, w_proj, xb, wqkvb, wprojb);
  gemm256<<<192, 512, 0, stream>>>(xb, wqkvb, b_qkv, qb, kb, vtb);
  attn_fused<<<512, 256, 0, stream>>>(qb, kb, vtb, aob);
  gemm_proj<<<256, 256, 0, stream>>>(aob, wprojb, b_proj, out);
}

// Round 21
// 114.735 us; speedup vs baseline: 1.0153x; 1.0036x over previous
//
#include <hip/hip_runtime.h>

typedef short short8 __attribute__((ext_vector_type(8)));
typedef short short4v __attribute__((ext_vector_type(4)));
typedef float f32x4 __attribute__((ext_vector_type(4)));
typedef float float4v __attribute__((ext_vector_type(4)));
typedef int int4v __attribute__((ext_vector_type(4)));
typedef int int2v __attribute__((ext_vector_type(2)));

__device__ __forceinline__ short f2bf(float f) {
  union { float f; unsigned u; } v; v.f = f;
  unsigned r = v.u + 0x7FFFu + ((v.u >> 16) & 1u);
  return (short)(r >> 16);
}

__device__ __forceinline__ unsigned cvtpk_bf16(float lo, float hi) {
  unsigned r;
  asm("v_cvt_pk_bf16_f32 %0, %1, %2" : "=v"(r) : "v"(lo), "v"(hi));
  return r;  // lo16 = bf16(lo), hi16 = bf16(hi)
}

// async global->LDS, 16B per lane; dest must be linear (wave base + lane*16)
#define GLD16(gp, lp)                                                   \
  __builtin_amdgcn_global_load_lds(                                     \
      (const __attribute__((address_space(1))) void*)(gp),              \
      (__attribute__((address_space(3))) void*)(lp), 16, 0, 0)

// Q scale: softmax uses exp2, so fold log2(e) into the 1/sqrt(64) scale
#define QSCALE 0.18033688011112042f

// ---------------- fused fp32 -> bf16 convert, 32B/thread (x | w_qkv | w_proj) ----------------
// 2 float4 loads per thread (2 outstanding -> MLP) + one 16B short8 store.
// Segment boundaries in 8-float units: x 524288, wq 393216, wp 131072
// (cumulative 524288 / 917504 / 1048576 — all multiples of 256, so the
// 3-way select is block-uniform). Grid 4096 x 256.
__global__ __launch_bounds__(256) void cvt_all(
    const float* __restrict__ x, const float* __restrict__ wq, const float* __restrict__ wp,
    short* __restrict__ xb, short* __restrict__ wqb, short* __restrict__ wpb) {
  int i = blockIdx.x * 256 + threadIdx.x;  // in 8-float units; total 1048576
  const float* s; short* d; int off;
  if (i < 524288)      { s = x;  d = xb;  off = i; }
  else if (i < 917504) { s = wq; d = wqb; off = i - 524288; }
  else                 { s = wp; d = wpb; off = i - 917504; }
  float4v v0 = ((const float4v*)s)[2 * off];
  float4v v1 = ((const float4v*)s)[2 * off + 1];
  short8 o;
  o[0] = f2bf(v0.x); o[1] = f2bf(v0.y); o[2] = f2bf(v0.z); o[3] = f2bf(v0.w);
  o[4] = f2bf(v1.x); o[5] = f2bf(v1.y); o[6] = f2bf(v1.z); o[7] = f2bf(v1.w);
  ((short8*)d)[off] = o;
}

// ---------------- qkv GEMM: 256x256 tile, 4-phase/K-tile counted-vmcnt (R17) ----------------
__global__ __launch_bounds__(512, 2) void gemm256(
    const short* __restrict__ A, const short* __restrict__ Bw,
    const float* __restrict__ bias,
    short* __restrict__ qo, short* __restrict__ ko, short* __restrict__ vto) {
  __shared__ char lds[131072];
  const int t = threadIdx.x;
  const int lane = t & 63, wid = t >> 6;
  const int g = lane >> 4, l15 = lane & 15;
  const int wr = wid >> 2, wc = wid & 3;
  const int bid = blockIdx.x;
  // bijective: xcd = bid&7 -> bm = xcd*2 + bit3, bn = bid>>4
  const int bm0 = ((bid & 7) * 2 + ((bid >> 3) & 1)) * 256;
  const int bn0 = (bid >> 4) * 256;

  const int srow = t >> 3;
  const int ssub = (t & 7) ^ ((t >> 3) & 7);

  const int swz = (l15 & 7) << 4;
  int inrow[2];
  inrow[0] = (g * 16) ^ swz;
  inrow[1] = (64 + g * 16) ^ swz;
  const int bRow0 = (wc & 1) * 64;

  f32x4 acc[8][4] = {};

  auto stageHT = [&](int b, int kt, int ht) {
    const int isB = ht >> 1, hh = ht & 1;
    const short* mat = isB ? Bw : A;
    const int base = isB ? bn0 : bm0;
    const short* src = mat + (size_t)(base + hh * 128 + srow) * 1024 + kt * 64 + ssub * 8;
    char* dst = lds + b * 65536 + isB * 32768 + hh * 16384 + t * 16;
    GLD16(src, dst);
    GLD16(src + 64 * 1024, dst + 8192);
  };

#pragma unroll
  for (int ht = 0; ht < 4; ++ht) stageHT(0, 0, ht);

  for (int k = 0; k < 16; ++k) {
    const int buf = k & 1;
    const char* Ab = lds + buf * 65536 + wr * 16384;
    const char* Bb = lds + buf * 65536 + 32768 + (wc >> 1) * 16384;
    short8 bB[4][2];
#pragma unroll
    for (int mp = 0; mp < 4; ++mp) {
      if (k + 1 < 16) stageHT(buf ^ 1, k + 1, mp);
      __builtin_amdgcn_sched_barrier(0);
      if (mp == 0) {
        if (k + 1 < 16) asm volatile("s_waitcnt vmcnt(2)" ::: "memory");
        else            asm volatile("s_waitcnt vmcnt(0)" ::: "memory");
        __builtin_amdgcn_s_barrier();
        __builtin_amdgcn_sched_barrier(0);
#pragma unroll
        for (int n = 0; n < 4; ++n)
#pragma unroll
          for (int kk = 0; kk < 2; ++kk)
            bB[n][kk] = *(const short8*)(Bb + (bRow0 + n * 16 + l15) * 128 + inrow[kk]);
      }
      short8 aA[2][2];
#pragma unroll
      for (int mm = 0; mm < 2; ++mm)
#pragma unroll
        for (int kk = 0; kk < 2; ++kk)
          aA[mm][kk] = *(const short8*)(Ab + ((mp * 2 + mm) * 16 + l15) * 128 + inrow[kk]);
      __builtin_amdgcn_s_setprio(1);
#pragma unroll
      for (int mm = 0; mm < 2; ++mm)
#pragma unroll
        for (int n = 0; n < 4; ++n)
#pragma unroll
          for (int kk = 0; kk < 2; ++kk)
            acc[mp * 2 + mm][n] = __builtin_amdgcn_mfma_f32_16x16x32_bf16(
                aA[mm][kk], bB[n][kk], acc[mp * 2 + mm][n], 0, 0, 0);
      __builtin_amdgcn_s_setprio(0);
      if (mp == 3) {
        __builtin_amdgcn_sched_barrier(0);
        __builtin_amdgcn_s_barrier();
        __builtin_amdgcn_sched_barrier(0);
      }
    }
  }

  const int which = bn0 >> 10;
  if (which == 2) {
#pragma unroll
    for (int m = 0; m < 8; ++m) {
#pragma unroll
      for (int n = 0; n < 4; ++n) {
        int gcol = bn0 + wc * 64 + n * 16 + l15;
        int w1 = gcol & 1023;
        int h = w1 >> 6, dd = w1 & 63;
        float bv = bias[gcol];
        int grow0 = bm0 + wr * 128 + m * 16 + g * 4;
        int b_ = grow0 >> 11, n0 = grow0 & 2047;
        int bh = b_ * 16 + h;
        int nl = n0 & 63;
        int np = (n0 & ~63) | (nl & 32) | ((nl & 12) << 1) | ((nl & 16) >> 2);
        int2v pk;
        pk.x = (int)cvtpk_bf16(acc[m][n][0] + bv, acc[m][n][1] + bv);
        pk.y = (int)cvtpk_bf16(acc[m][n][2] + bv, acc[m][n][3] + bv);
        *(int2v*)(vto + ((size_t)bh * 64 + dd) * 2048 + np) = pk;
      }
    }
  } else {
    short* dst = (which == 0) ? qo : ko;
    const float sc = (which == 0) ? QSCALE : 1.0f;
#pragma unroll
    for (int m = 0; m < 8; ++m) {
#pragma unroll
      for (int n = 0; n < 4; ++n) {
        int gcol = bn0 + wc * 64 + n * 16 + l15;
        int w1 = gcol & 1023;
        int h = w1 >> 6, dd = w1 & 63;
        float bv = bias[gcol];
#pragma unroll
        for (int r = 0; r < 4; ++r) {
          int grow = bm0 + wr * 128 + m * 16 + g * 4 + r;
          int b_ = grow >> 11, n2 = grow & 2047;
          int bh = b_ * 16 + h;
          dst[((size_t)bh * 2048 + n2) * 64 + dd] = f2bf((acc[m][n][r] + bv) * sc);
        }
      }
    }
  }
}

// ---------------- proj GEMM (R14-proven): BK=32, 3 slots, depth-3 vmcnt ----------------
__global__ __launch_bounds__(256, 3) void gemm_proj(
    const short* __restrict__ A, const short* __restrict__ Bw,
    const float* __restrict__ bias, float* __restrict__ outf) {
  __shared__ short As[3][128 * 32];
  __shared__ short Bs[3][128 * 32];
  const int t = threadIdx.x;
  const int lane = t & 63, wid = t >> 6;
  const int g = lane >> 4, l15 = lane & 15;
  const int wr = (wid >> 1) * 64, wc = (wid & 1) * 64;
  const int bid = blockIdx.x;
  const int bm0 = ((bid & 7) * 4 + ((bid >> 3) & 3)) * 128;
  const int bn0 = (bid >> 5) * 128;

  const int sr = t >> 2;
  const int csrc = (t & 3) ^ ((t >> 3) & 3);

  const int gx = (g ^ ((l15 >> 1) & 3)) << 4;
  int aoff[4], boff[4];
#pragma unroll
  for (int f = 0; f < 4; ++f) {
    aoff[f] = (wr + f * 16 + l15) * 64 + gx;
    boff[f] = (wc + f * 16 + l15) * 64 + gx;
  }

  f32x4 acc[4][4] = {};

  auto stage = [&](int offB, int k0) {
#pragma unroll
    for (int i = 0; i < 2; ++i) {
      int row = i * 64 + sr;
      char* ldsA = (char*)&As[0][0] + offB + (i * 256 + (t & ~63)) * 16;
      char* ldsB = (char*)&Bs[0][0] + offB + (i * 256 + (t & ~63)) * 16;
      GLD16(A + (size_t)(bm0 + row) * 1024 + k0 + csrc * 8, ldsA);
      GLD16(Bw + (size_t)(bn0 + row) * 1024 + k0 + csrc * 8, ldsB);
    }
  };

  stage(0, 0);
  stage(8192, 32);
  stage(16384, 64);
  int off = 0;

  for (int it = 0; it < 32; ++it) {
    if (it < 30)       asm volatile("s_waitcnt vmcnt(8)" ::: "memory");
    else if (it == 30) asm volatile("s_waitcnt vmcnt(4)" ::: "memory");
    else               asm volatile("s_waitcnt vmcnt(0)" ::: "memory");
    __builtin_amdgcn_s_barrier();
    __builtin_amdgcn_sched_barrier(0);
    const char* AsB = (const char*)&As[0][0] + off;
    const char* BsB = (const char*)&Bs[0][0] + off;
    short8 a[4], b[4];
#pragma unroll
    for (int mi = 0; mi < 4; ++mi) a[mi] = *(const short8*)(AsB + aoff[mi]);
#pragma unroll
    for (int ni = 0; ni < 4; ++ni) b[ni] = *(const short8*)(BsB + boff[ni]);
#pragma unroll
    for (int mi = 0; mi < 4; ++mi)
#pragma unroll
      for (int ni = 0; ni < 4; ++ni)
        acc[mi][ni] = __builtin_amdgcn_mfma_f32_16x16x32_bf16(a[mi], b[ni], acc[mi][ni], 0, 0, 0);
    __builtin_amdgcn_sched_barrier(0);
    __builtin_amdgcn_s_barrier();
    __builtin_amdgcn_sched_barrier(0);
    if (it + 3 < 32) stage(off, (it + 3) * 32);
    off = (off == 16384) ? 0 : off + 8192;
  }

#pragma unroll
  for (int mi = 0; mi < 4; ++mi) {
#pragma unroll
    for (int ni = 0; ni < 4; ++ni) {
      int gcol = bn0 + wc + ni * 16 + l15;
      float bv = bias[gcol];
#pragma unroll
      for (int r = 0; r < 4; ++r) {
        int grow = bm0 + wr + mi * 16 + g * 4 + r;
        outf[(size_t)grow * 1024 + gcol] = acc[mi][ni][r] + bv;
      }
    }
  }
}

// ---------------- flash attention (R10-proven, 58.7us, defer-max) ----------------
__global__ __launch_bounds__(256, 2) void attn_fused(
    const short* __restrict__ Qg, const short* __restrict__ Kg,
    const short* __restrict__ Vtg, short* __restrict__ AO) {
  __shared__ short Ks[4][64 * 64];  // slot = buf*2 + sub, 8KB each
  __shared__ short Vs[4][64 * 64];
  const int bid = blockIdx.x;
  const int bh = bid & 31, qt = bid >> 5;
  const int t = threadIdx.x, wid = t >> 6, lane = t & 63;
  const int g = lane >> 4, l15 = lane & 15;
  const int q0w = qt * 128 + wid * 32;
  const short* qb = Qg + ((size_t)bh * 2048 + q0w) * 64;
  const short* kb = Kg + (size_t)bh * 2048 * 64;
  const short* vb = Vtg + (size_t)bh * 64 * 2048;

  const int srow = t >> 3;
  const int ssub = (t & 7) ^ (srow & 7);
  const short* ksrc0 = kb + srow * 64 + ssub * 8;
  const short* vsrc0 = vb + (size_t)srow * 2048 + ssub * 8;

  const int swz = (l15 & 7) << 4;
  int foff[2][4];
#pragma unroll
  for (int kk = 0; kk < 2; ++kk)
#pragma unroll
    for (int f = 0; f < 4; ++f)
      foff[kk][f] = ((f * 16 + l15) * 128 + kk * 64 + g * 16) ^ swz;

  short8 bq[2][2];
#pragma unroll
  for (int qf = 0; qf < 2; ++qf)
#pragma unroll
    for (int kk = 0; kk < 2; ++kk)
      bq[qf][kk] = *(const short8*)(qb + (qf * 16 + l15) * 64 + kk * 32 + g * 8);

  auto stageP = [&](int buf, int p) {
    const int n0 = p * 128;
#pragma unroll
    for (int sub = 0; sub < 2; ++sub) {
      const int nn = n0 + sub * 64;
      char* ldsK = (char*)&Ks[buf * 2 + sub][0] + wid * 1024;
      char* ldsV = (char*)&Vs[buf * 2 + sub][0] + wid * 1024;
#pragma unroll
      for (int i = 0; i < 2; ++i) {
        GLD16(ksrc0 + (size_t)(nn + i * 32) * 64, ldsK + i * 4096);
        GLD16(vsrc0 + (size_t)i * 32 * 2048 + nn, ldsV + i * 4096);
      }
    }
  };

  stageP(0, 0);
  stageP(1, 1);

  f32x4 acc[2][4] = {};
  float mrun[2] = {-3.0e38f, -3.0e38f}, lrun[2] = {0.f, 0.f};

  for (int p = 0; p < 16; ++p) {
    if (p == 15) asm volatile("s_waitcnt vmcnt(0)" ::: "memory");
    else         asm volatile("s_waitcnt vmcnt(8)" ::: "memory");
    __builtin_amdgcn_s_barrier();
    __builtin_amdgcn_sched_barrier(0);
    const int buf = p & 1;

#pragma unroll
    for (int sub = 0; sub < 2; ++sub) {
      const char* KsB = (const char*)&Ks[buf * 2 + sub][0];
      const char* VsB = (const char*)&Vs[buf * 2 + sub][0];

      f32x4 s[2][4] = {};
#pragma unroll
      for (int kk = 0; kk < 2; ++kk) {
        short8 ak[4];
#pragma unroll
        for (int kf = 0; kf < 4; ++kf) ak[kf] = *(const short8*)(KsB + foff[kk][kf]);
#pragma unroll
        for (int kf = 0; kf < 4; ++kf)
#pragma unroll
          for (int qf = 0; qf < 2; ++qf)
            s[qf][kf] = __builtin_amdgcn_mfma_f32_16x16x32_bf16(ak[kf], bq[qf][kk], s[qf][kf], 0, 0, 0);
      }

      float pm[2];
#pragma unroll
      for (int qf = 0; qf < 2; ++qf) {
        float m0 = fmaxf(s[qf][0][0], s[qf][0][1]);
        m0 = fmaxf(fmaxf(m0, s[qf][0][2]), s[qf][0][3]);
#pragma unroll
        for (int kf = 1; kf < 4; ++kf) {
          m0 = fmaxf(fmaxf(m0, s[qf][kf][0]), s[qf][kf][1]);
          m0 = fmaxf(fmaxf(m0, s[qf][kf][2]), s[qf][kf][3]);
        }
        float x = fmaxf(m0, __shfl_xor(m0, 16));
        pm[qf] = fmaxf(x, __shfl_xor(x, 32));
      }

      if (!__all((pm[0] - mrun[0] <= 8.f) && (pm[1] - mrun[1] <= 8.f))) {
#pragma unroll
        for (int qf = 0; qf < 2; ++qf) {
          float mn = fmaxf(mrun[qf], pm[qf]);
          float alpha = __builtin_amdgcn_exp2f(mrun[qf] - mn);
          mrun[qf] = mn;
          lrun[qf] *= alpha;
#pragma unroll
          for (int df = 0; df < 4; ++df)
#pragma unroll
            for (int r = 0; r < 4; ++r) acc[qf][df][r] *= alpha;
        }
      }

      unsigned wpk[2][4][2];
#pragma unroll
      for (int qf = 0; qf < 2; ++qf) {
        float rs = 0.f;
        float pp[4][4];
#pragma unroll
        for (int kf = 0; kf < 4; ++kf)
#pragma unroll
          for (int r = 0; r < 4; ++r) {
            pp[kf][r] = __builtin_amdgcn_exp2f(s[qf][kf][r] - mrun[qf]);
            rs += pp[kf][r];
          }
        rs += __shfl_xor(rs, 16);
        rs += __shfl_xor(rs, 32);
        lrun[qf] += rs;
#pragma unroll
        for (int kf = 0; kf < 4; ++kf)
#pragma unroll
          for (int h = 0; h < 2; ++h)
            wpk[qf][kf][h] = cvtpk_bf16(pp[kf][2 * h], pp[kf][2 * h + 1]);
      }

#pragma unroll
      for (int kk = 0; kk < 2; ++kk) {
        short8 av[4];
#pragma unroll
        for (int df = 0; df < 4; ++df) av[df] = *(const short8*)(VsB + foff[kk][df]);
#pragma unroll
        for (int qf = 0; qf < 2; ++qf) {
          union { int4v i; short8 s; } pv;
          pv.i[0] = (int)wpk[qf][2 * kk][0];
          pv.i[1] = (int)wpk[qf][2 * kk][1];
          pv.i[2] = (int)wpk[qf][2 * kk + 1][0];
          pv.i[3] = (int)wpk[qf][2 * kk + 1][1];
#pragma unroll
          for (int df = 0; df < 4; ++df)
            acc[qf][df] = __builtin_amdgcn_mfma_f32_16x16x32_bf16(av[df], pv.s, acc[qf][df], 0, 0, 0);
        }
      }
    }

    __builtin_amdgcn_sched_barrier(0);
    __builtin_amdgcn_s_barrier();
    __builtin_amdgcn_sched_barrier(0);
    if (p + 2 < 16) stageP(buf, p + 2);
  }

  const int b_ = bh >> 4, h = bh & 15;
#pragma unroll
  for (int qf = 0; qf < 2; ++qf) {
    const float inv = 1.0f / lrun[qf];
    short* outp = AO + ((size_t)b_ * 2048 + q0w + qf * 16 + l15) * 1024 + h * 64 + g * 4;
#pragma unroll
    for (int df = 0; df < 4; ++df) {
      short4v o;
#pragma unroll
      for (int r = 0; r < 4; ++r) o[r] = f2bf(acc[qf][df][r] * inv);
      *(short4v*)(outp + df * 16) = o;
    }
  }
}

// ---------------- launch ----------------
extern "C" void kernel_launch(void* const* d_in, const int* in_sizes, int n_in,
                              void* d_out, int out_size, void* d_ws, size_t ws_size,
                              hipStream_t stream) {
  const float* x = (const float*)d_in[0];
  const float* w_qkv = (const float*)d_in[1];
  const float* b_qkv = (const float*)d_in[2];
  const float* w_proj = (const float*)d_in[3];
  const float* b_proj = (const float*)d_in[4];
  float* out = (float*)d_out;
  char* ws = (char*)d_ws;

  short* xb    = (short*)(ws + (size_t)0);
  short* wqkvb = (short*)(ws + ((size_t)8 << 20));
  short* wprojb= (short*)(ws + ((size_t)14 << 20));
  short* qb    = (short*)(ws + ((size_t)16 << 20));
  short* kb    = (short*)(ws + ((size_t)24 << 20));
  short* vtb   = (short*)(ws + ((size_t)32 << 20));
  short* aob   = (short*)(ws + ((size_t)40 << 20));

  cvt_all<<<4096, 256, 0, stream>>>(x, w_qkv, w_proj, xb, wqkvb, wprojb);
  gemm256<<<192, 512, 0, stream>>>(xb, wqkvb, b_qkv, qb, kb, vtb);
  attn_fused<<<512, 256, 0, stream>>>(qb, kb, vtb, aob);
  gemm_proj<<<256, 256, 0, stream>>>(aob, wprojb, b_proj, out);
}